// Round 8
// baseline (133.317 us; speedup 1.0000x reference)
//
#include <hip/hip_runtime.h>

typedef __attribute__((ext_vector_type(8))) short bf16x8;
typedef __attribute__((ext_vector_type(4))) float f32x4;

#define MFMA16(a, b, c) __builtin_amdgcn_mfma_f32_16x16x32_bf16(a, b, c, 0, 0, 0)

__device__ __forceinline__ unsigned short f2bf(float f) {
    unsigned u = __builtin_bit_cast(unsigned, f);
    u += 0x7FFFu + ((u >> 16) & 1u);          // RNE
    return (unsigned short)(u >> 16);
}
__device__ __forceinline__ float bf2f(unsigned short h) {
    return __builtin_bit_cast(float, (unsigned)h << 16);
}

// split8 via v_cvt_pk_bf16_f32 (RNE, 2 elems/op): hi plane + bf16(residual)
__device__ __forceinline__ void split8(const float* v, bf16x8& hi, bf16x8& lo) {
    unsigned* hp = reinterpret_cast<unsigned*>(&hi);
    unsigned* lp = reinterpret_cast<unsigned*>(&lo);
    #pragma unroll
    for (int q = 0; q < 4; ++q) {
        const float a = v[2 * q], b = v[2 * q + 1];
        unsigned hpair;
        asm("v_cvt_pk_bf16_f32 %0, %1, %2" : "=v"(hpair) : "v"(a), "v"(b));
        const float ha = __builtin_bit_cast(float, hpair << 16);
        const float hb = __builtin_bit_cast(float, hpair & 0xFFFF0000u);
        const float ra = a - ha, rb = b - hb;
        unsigned lpair;
        asm("v_cvt_pk_bf16_f32 %0, %1, %2" : "=v"(lpair) : "v"(ra), "v"(rb));
        hp[q] = hpair;
        lp[q] = lpair;
    }
}

// ---------------------------------------------------------------------------
// Prep: pqrs (interaction constants, PRE-SCALED by 2*log2(e)) + fragment-
// ordered split-bf16 weights. B-frag 16x16x32: lane l holds
// B[kt*32+(l>>4)*8+i][n*16+(l&15)], i<8.
// wsm = w2h[2048] | w2l[2048] | w3h[512] | w3l[512].
// ---------------------------------------------------------------------------
__global__ void prep_kernel(const float* __restrict__ W1,
                            const float* __restrict__ W2,
                            const float* __restrict__ W3,
                            const float* __restrict__ W_emb,
                            const float* __restrict__ b_emb,
                            const float* __restrict__ M,
                            float* __restrict__ pqrs,
                            unsigned short* __restrict__ w1h,
                            unsigned short* __restrict__ w1l,
                            unsigned short* __restrict__ wsm) {
    const int t = threadIdx.x;
    const float C2 = 2.8853900817779268f;   // 2*log2(e)
    {
        const int j = t >> 4;
        const int i = t & 15;
        float mr[8], mb[8];
        #pragma unroll
        for (int e = 0; e < 8; ++e) {
            float ar = 0.f, ab = 0.f;
            #pragma unroll
            for (int f = 0; f < 8; ++f) {
                const float m = M[e * 8 + f];
                ar = fmaf(m, W_emb[(16 + j) * 8 + f], ar);
                ab = fmaf(m, b_emb[(16 + j) * 8 + f], ab);
            }
            mr[e] = ar; mb[e] = ab;
        }
        float P = 0.f, Q = 0.f, R = 0.f, S = 0.f;
        #pragma unroll
        for (int e = 0; e < 8; ++e) {
            const float lw = W_emb[i * 8 + e];
            const float lb = b_emb[i * 8 + e];
            P = fmaf(lw, mr[e], P);
            Q = fmaf(lw, mb[e], Q);
            R = fmaf(lb, mr[e], R);
            S = fmaf(lb, mb[e], S);
        }
        pqrs[0 * 256 + j * 16 + i] = C2 * P;
        pqrs[1 * 256 + j * 16 + i] = C2 * Q;
        pqrs[2 * 256 + j * 16 + i] = C2 * R;
        pqrs[3 * 256 + j * 16 + i] = C2 * S;
    }
    for (int e = 0; e < 32; ++e) {
        const int idx = t * 32 + e;
        const int i = idx & 7, lane = (idx >> 3) & 63;
        const int n = (idx >> 9) & 3, kt = idx >> 11;
        const int k = kt * 32 + (lane >> 4) * 8 + i;
        const int c = n * 16 + (lane & 15);
        const float v = W1[k * 64 + c];
        const unsigned short h = f2bf(v);
        w1h[idx] = h;
        w1l[idx] = f2bf(v - bf2f(h));
    }
    for (int e = 0; e < 8; ++e) {
        const int idx = t * 8 + e;
        const int i = idx & 7, lane = (idx >> 3) & 63;
        const int n = (idx >> 9) & 1, kt = (idx >> 10) & 1;
        const int k = kt * 32 + (lane >> 4) * 8 + i;
        const int c = n * 16 + (lane & 15);
        const float v = W2[k * 32 + c];
        const unsigned short h = f2bf(v);
        wsm[idx] = h;
        wsm[2048 + idx] = f2bf(v - bf2f(h));
    }
    for (int e = 0; e < 2; ++e) {
        const int idx = t * 2 + e;
        const int i = idx & 7, lane = (idx >> 3) & 63;
        const int k = (lane >> 4) * 8 + i;
        const int c = lane & 15;
        const float v = W3[k * 16 + c];
        const unsigned short h = f2bf(v);
        wsm[4096 + idx] = h;
        wsm[4608 + idx] = f2bf(v - bf2f(h));
    }
}

// ---------------------------------------------------------------------------
// Fused kernel (R5 structure, verified). Wave = 128 tower-rows (8 tiles of
// 16) = 64 original rows. ONE change vs R5: odd tiles use a second transpose
// buffer (s_tr2) so tile k+1's layer-1 LDS writes don't WAR-serialize
// against tile k's layer-3 reads -> compiler can software-pipeline 2 tiles.
// Epilogue: lane l owns ONE original row (tower-rows 2l, 2l+1).
// h3 stash transposed [ch][tower_row], stride 130. No __syncthreads.
// ---------------------------------------------------------------------------
__global__ __launch_bounds__(256, 3) void fused_kernel(
    const float* __restrict__ x,
    const unsigned short* __restrict__ w1h,
    const unsigned short* __restrict__ w1l,
    const unsigned short* __restrict__ wsm,
    const float* __restrict__ b1, const float* __restrict__ b2,
    const float* __restrict__ b3,
    const float* __restrict__ pqrs,
    const float* __restrict__ W_out, const float* __restrict__ b_out,
    float* __restrict__ y) {
    __shared__ float s_tr[4][16 * 68];     // per-wave transpose tile (even)
    __shared__ float s_tr2[4][16 * 68];    // per-wave transpose tile (odd)
    __shared__ float s_h3[4][16 * 130];    // per-wave h3^T stash

    const int tid = threadIdx.x;
    const int l  = tid & 63;
    const int wv = tid >> 6;
    const int lm = l & 15;
    const int lg = l >> 4;

    const unsigned short* w2h = wsm;
    const unsigned short* w2l = wsm + 2048;
    const unsigned short* w3h = wsm + 4096;
    const unsigned short* w3l = wsm + 4608;

    float b1v[4], b2v[2];
    #pragma unroll
    for (int n = 0; n < 4; ++n) b1v[n] = b1[n * 16 + lm];
    #pragma unroll
    for (int n = 0; n < 2; ++n) b2v[n] = b2[n * 16 + lm];
    const float b3v = b3[lm];

    const long tr0 = (long)blockIdx.x * 512 + wv * 128;  // wave's first tower-row
    float* h3b = s_h3[wv];

    float4 xb[2][8];
    {
        const float* xp = x + (tr0 + lm) * 128 + lg * 8;
        #pragma unroll
        for (int kt = 0; kt < 4; ++kt) {
            xb[0][2 * kt]     = *(const float4*)(xp + kt * 32);
            xb[0][2 * kt + 1] = *(const float4*)(xp + kt * 32 + 4);
        }
    }

    #pragma unroll
    for (int tile = 0; tile < 8; ++tile) {
        const int cur = tile & 1, nxt = cur ^ 1;
        float* tb = (tile & 1) ? s_tr2[wv] : s_tr[wv];   // parity buffer
        if (tile < 7) {   // prefetch next tile's x
            const float* xp = x + (tr0 + (tile + 1) * 16 + lm) * 128 + lg * 8;
            #pragma unroll
            for (int kt = 0; kt < 4; ++kt) {
                xb[nxt][2 * kt]     = *(const float4*)(xp + kt * 32);
                xb[nxt][2 * kt + 1] = *(const float4*)(xp + kt * 32 + 4);
            }
        }
        // ---- layer 1: (16x128)@(128x64), split-bf16
        f32x4 acc[4];
        #pragma unroll
        for (int n = 0; n < 4; ++n) acc[n] = f32x4{b1v[n], b1v[n], b1v[n], b1v[n]};
        #pragma unroll
        for (int kt = 0; kt < 4; ++kt) {
            const float4 a = xb[cur][2 * kt], b = xb[cur][2 * kt + 1];
            const float xv[8] = {a.x, a.y, a.z, a.w, b.x, b.y, b.z, b.w};
            bf16x8 xh, xl; split8(xv, xh, xl);
            #pragma unroll
            for (int n = 0; n < 4; ++n) {
                const int fo = ((kt * 4 + n) * 64 + l) * 8;
                const bf16x8 wh = *(const bf16x8*)(w1h + fo);
                const bf16x8 wl = *(const bf16x8*)(w1l + fo);
                acc[n] = MFMA16(xh, wh, acc[n]);
                acc[n] = MFMA16(xl, wh, acc[n]);
                acc[n] = MFMA16(xh, wl, acc[n]);
            }
        }
        // ---- transpose h1 via LDS (relu on write)
        #pragma unroll
        for (int n = 0; n < 4; ++n)
            #pragma unroll
            for (int r = 0; r < 4; ++r)
                tb[(lg * 4 + r) * 68 + n * 16 + lm] = fmaxf(acc[n][r], 0.f);
        // ---- layer 2: (16x64)@(64x32)
        f32x4 acc2[2];
        #pragma unroll
        for (int n = 0; n < 2; ++n) acc2[n] = f32x4{b2v[n], b2v[n], b2v[n], b2v[n]};
        #pragma unroll
        for (int kt = 0; kt < 2; ++kt) {
            const float* ap = tb + lm * 68 + kt * 32 + lg * 8;
            const float4 h0 = *(const float4*)(ap);
            const float4 h1 = *(const float4*)(ap + 4);
            const float hv[8] = {h0.x, h0.y, h0.z, h0.w, h1.x, h1.y, h1.z, h1.w};
            bf16x8 hh, hl; split8(hv, hh, hl);
            #pragma unroll
            for (int n = 0; n < 2; ++n) {
                const int fo = ((kt * 2 + n) * 64 + l) * 8;
                const bf16x8 wh = *(const bf16x8*)(w2h + fo);
                const bf16x8 wl = *(const bf16x8*)(w2l + fo);
                acc2[n] = MFMA16(hh, wh, acc2[n]);
                acc2[n] = MFMA16(hl, wh, acc2[n]);
                acc2[n] = MFMA16(hh, wl, acc2[n]);
            }
        }
        // ---- transpose h2 (reuse tb; same-wave LDS ordering is in-order)
        #pragma unroll
        for (int n = 0; n < 2; ++n)
            #pragma unroll
            for (int r = 0; r < 4; ++r)
                tb[(lg * 4 + r) * 68 + n * 16 + lm] = fmaxf(acc2[n][r], 0.f);
        // ---- layer 3: (16x32)@(32x16)
        f32x4 acc3 = f32x4{b3v, b3v, b3v, b3v};
        {
            const float* ap = tb + lm * 68 + lg * 8;
            const float4 h0 = *(const float4*)(ap);
            const float4 h1 = *(const float4*)(ap + 4);
            const float hv[8] = {h0.x, h0.y, h0.z, h0.w, h1.x, h1.y, h1.z, h1.w};
            bf16x8 hh, hl; split8(hv, hh, hl);
            const bf16x8 wh = *(const bf16x8*)(w3h + l * 8);
            const bf16x8 wl = *(const bf16x8*)(w3l + l * 8);
            acc3 = MFMA16(hh, wh, acc3);
            acc3 = MFMA16(hl, wh, acc3);
            acc3 = MFMA16(hh, wl, acc3);
        }
        // ---- stash h3 transposed: h3b[ch=lm][row = tile*16+lg*4+r] (relu)
        #pragma unroll
        for (int r = 0; r < 4; ++r)
            h3b[lm * 130 + tile * 16 + lg * 4 + r] = fmaxf(acc3[r], 0.f);
    }

    // ---- epilogue: lane l owns original row (tr0>>1)+l; towers 2l, 2l+1
    float oL[16], oR[16];
    #pragma unroll
    for (int c = 0; c < 16; ++c) {
        const float2 v = *(const float2*)(h3b + c * 130 + 2 * l);
        oL[c] = v.x;
        oR[c] = v.y;
    }

    // interaction: z' = 2*log2e*(oL*oR*P + oL*Q + oR*R + S) [scale folded in
    // prep]; g = 1 - 2*rcp(2^z' + 1); accumulate rc, fix up 16-2*sum at end
    float sir[16];
    #pragma unroll
    for (int i = 0; i < 16; ++i) sir[i] = 0.f;
    float sjv[16];
    #pragma unroll
    for (int j = 0; j < 16; ++j) {
        const float r = oR[j];
        const float* __restrict__ Pr = pqrs +       j * 16;
        const float* __restrict__ Qr = pqrs + 256 + j * 16;
        const float* __restrict__ Rr = pqrs + 512 + j * 16;
        const float* __restrict__ Sr = pqrs + 768 + j * 16;
        float accr = 0.f;
        #pragma unroll
        for (int i = 0; i < 16; ++i) {
            const float t1 = fmaf(r, Pr[i], Qr[i]);
            const float t2 = fmaf(r, Rr[i], Sr[i]);
            const float z  = fmaf(oL[i], t1, t2);
            const float e  = __builtin_amdgcn_exp2f(z);
            const float rc = __builtin_amdgcn_rcpf(e + 1.0f);
            accr   += rc;
            sir[i] += rc;
        }
        sjv[j] = accr;
    }
    // sj[j] = 16 - 2*sum(rc); si[i] likewise
    #pragma unroll
    for (int i = 0; i < 16; ++i) {
        sjv[i] = fmaf(-2.f, sjv[i], 16.f);
        sir[i] = fmaf(-2.f, sir[i], 16.f);
    }

    {   // lr = softmax(sj) scales oL
        float mx = sjv[0];
        #pragma unroll
        for (int i = 1; i < 16; ++i) mx = fmaxf(mx, sjv[i]);
        float s = 0.f; float ex[16];
        #pragma unroll
        for (int i = 0; i < 16; ++i) { ex[i] = __expf(sjv[i] - mx); s += ex[i]; }
        const float inv = __builtin_amdgcn_rcpf(s);
        #pragma unroll
        for (int i = 0; i < 16; ++i) oL[i] *= ex[i] * inv;
    }
    {   // rl = softmax(si) scales oR
        float mx = sir[0];
        #pragma unroll
        for (int i = 1; i < 16; ++i) mx = fmaxf(mx, sir[i]);
        float s = 0.f; float ex[16];
        #pragma unroll
        for (int i = 0; i < 16; ++i) { ex[i] = __expf(sir[i] - mx); s += ex[i]; }
        const float inv = __builtin_amdgcn_rcpf(s);
        #pragma unroll
        for (int i = 0; i < 16; ++i) oR[i] *= ex[i] * inv;
    }

    float yv[16];
    #pragma unroll
    for (int oo = 0; oo < 16; ++oo) yv[oo] = b_out[oo];
    #pragma unroll
    for (int c = 0; c < 16; ++c) {
        const float cl = oL[c];
        const float cr = oR[c];
        const float* __restrict__ wl = W_out + c * 16;
        const float* __restrict__ wt = W_out + (16 + c) * 16;
        #pragma unroll
        for (int oo = 0; oo < 16; ++oo) {
            yv[oo] = fmaf(cl, wl[oo], yv[oo]);
            yv[oo] = fmaf(cr, wt[oo], yv[oo]);
        }
    }

    float* __restrict__ yo = y + ((tr0 >> 1) + l) * 16;
    #pragma unroll
    for (int q = 0; q < 4; ++q) {
        float4 v;
        v.x = fmaxf(yv[q * 4 + 0], 0.f);
        v.y = fmaxf(yv[q * 4 + 1], 0.f);
        v.z = fmaxf(yv[q * 4 + 2], 0.f);
        v.w = fmaxf(yv[q * 4 + 3], 0.f);
        *reinterpret_cast<float4*>(yo + q * 4) = v;
    }
}

extern "C" void kernel_launch(void* const* d_in, const int* in_sizes, int n_in,
                              void* d_out, int out_size, void* d_ws, size_t ws_size,
                              hipStream_t stream) {
    const float* x     = (const float*)d_in[0];
    const float* W1    = (const float*)d_in[1];
    const float* b1    = (const float*)d_in[2];
    const float* W2    = (const float*)d_in[3];
    const float* b2    = (const float*)d_in[4];
    const float* W3    = (const float*)d_in[5];
    const float* b3    = (const float*)d_in[6];
    const float* W_emb = (const float*)d_in[7];
    const float* b_emb = (const float*)d_in[8];
    const float* M     = (const float*)d_in[9];
    const float* W_out = (const float*)d_in[10];
    const float* b_out = (const float*)d_in[11];
    float* y = (float*)d_out;

    float* pqrs = (float*)d_ws;                                    // 4 KB
    unsigned short* w1h = (unsigned short*)((char*)d_ws + 4096);   // 16 KB
    unsigned short* w1l = w1h + 8192;                              // 16 KB
    unsigned short* wsm = w1l + 8192;                              // 10 KB

    const int nrows = in_sizes[0] / 256;

    prep_kernel<<<1, 256, 0, stream>>>(W1, W2, W3, W_emb, b_emb, M,
                                       pqrs, w1h, w1l, wsm);
    const int grid = nrows / 256;   // B = 262144 -> 1024 blocks
    fused_kernel<<<grid, 256, 0, stream>>>(x, w1h, w1l, wsm,
                                           b1, b2, b3, pqrs, W_out, b_out, y);
}